// Round 15
// baseline (351.097 us; speedup 1.0000x reference)
//
#include <hip/hip_runtime.h>

#define DEVI static __device__ __forceinline__

namespace {

constexpr int NV   = 120000;
constexpr int ND   = 30000;
constexpr int NV2  = 60000;
constexpr int NPTS = 400000;
constexpr int C    = 128;

constexpr int NSEG  = NV2 + ND;        // combined histogram length (90000)
constexpr int TOTAL = NPTS + NV;       // combined scan total
constexpr int ST    = 512;             // scan tile (elements per block)

typedef __attribute__((ext_vector_type(8))) short bf16x8;   // 8 bf16 = 4 VGPR
typedef __attribute__((ext_vector_type(4))) float f32x4;    // MFMA accumulator

DEVI float lrelu(float x){ return x > 0.f ? x : 0.1f*x; }

DEVI unsigned short f2bf(float f){            // f32 -> bf16 RNE
  unsigned u = __float_as_uint(f);
  return (unsigned short)((u + 0x7FFFu + ((u >> 16) & 1u)) >> 16);
}
DEVI float bf2f(unsigned short h){ return __uint_as_float((unsigned)h << 16); }

DEVI void split8(const float* v, bf16x8& h, bf16x8& lo){
  #pragma unroll
  for (int j = 0; j < 8; ++j){
    unsigned short hb = f2bf(v[j]);
    h[j]  = (short)hb;
    lo[j] = (short)f2bf(v[j] - bf2f(hb));
  }
}

// ======== setup: weight pack (blocks 0..31) + combined histogram (rest) ====
// pw layout: [w][hi 16384 | lo 16384], w = Win, Wo1t, Wo1b, Wo2.
// B-frag order: frag=(nt*4+ks)*64+lane holds B[k][n]: n=nt*16+(lane&15),
// k=ks*32+(lane>>4)*8+j.
__global__ void k_setup(const float* __restrict__ W0, const float* __restrict__ W1,
                        const float* __restrict__ W2, const float* __restrict__ W3,
                        unsigned short* __restrict__ pw,
                        const int* __restrict__ cin, const int* __restrict__ inv,
                        int* __restrict__ histc){
  int bid = blockIdx.x;
  if (bid < 32){
    int w = bid >> 3;
    const float* W = (w == 0) ? W0 : (w == 1) ? W1 : (w == 2) ? W2 : W3;
    unsigned short* ph = pw + (size_t)w * 32768;
    unsigned short* pl = ph + 16384;
    int frag = (bid & 7) * 256 + threadIdx.x;
    int lane = frag & 63;
    int ks = (frag >> 6) & 3;
    int nt = frag >> 8;
    int n  = nt * 16 + (lane & 15);
    int k0 = ks * 32 + (lane >> 4) * 8;
    int ob = frag * 8;
    #pragma unroll
    for (int j = 0; j < 8; ++j){
      float w_ = W[(size_t)(k0 + j) * 128 + n];
      unsigned short hi = f2bf(w_);
      ph[ob + j] = hi;
      pl[ob + j] = f2bf(w_ - bf2f(hi));
    }
  } else {
    int i = (bid - 32) * 256 + threadIdx.x;
    if (i < NPTS) atomicAdd(&histc[cin[i]], 1);
    else if (i < TOTAL) atomicAdd(&histc[NV2 + inv[i - NPTS]], 1);
  }
}

// ======== hierarchical scan (3-pass; r10-proven) ========

__global__ __launch_bounds__(256) void k_tilesum(const int* __restrict__ h, int n,
                                                 int* __restrict__ ts){
  __shared__ int red[256];
  int base = blockIdx.x * ST;
  int t = threadIdx.x;
  int a0 = base + t, a1 = base + t + 256;
  red[t] = (a0 < n ? h[a0] : 0) + (a1 < n ? h[a1] : 0);
  __syncthreads();
  for (int d = 128; d > 0; d >>= 1){
    if (t < d) red[t] += red[t + d];
    __syncthreads();
  }
  if (t == 0) ts[blockIdx.x] = red[0];
}

__global__ __launch_bounds__(256) void k_scantiles(int* __restrict__ ts, int nt){
  __shared__ int ls[256];
  int t = threadIdx.x;
  ls[t] = t < nt ? ts[t] : 0;
  __syncthreads();
  for (int d = 1; d < 256; d <<= 1){
    int v = t >= d ? ls[t - d] : 0;
    __syncthreads();
    ls[t] += v;
    __syncthreads();
  }
  if (t < nt) ts[t] = (t == 0) ? 0 : ls[t - 1];
}

__global__ __launch_bounds__(256) void k_scanwrite(
    const int* __restrict__ h, const int* __restrict__ ts, int n,
    int* __restrict__ off, int* __restrict__ next){
  __shared__ int ls[256];
  int base = blockIdx.x * ST;
  int t = threadIdx.x;
  int i0 = base + 2 * t, i1 = i0 + 1;
  int v0 = (i0 < n) ? h[i0] : 0;
  int v1 = (i1 < n) ? h[i1] : 0;
  ls[t] = v0 + v1;
  __syncthreads();
  for (int d = 1; d < 256; d <<= 1){
    int v = t >= d ? ls[t - d] : 0;
    __syncthreads();
    ls[t] += v;
    __syncthreads();
  }
  int ex = ts[blockIdx.x] + ((t == 0) ? 0 : ls[t - 1]);
  if (i0 < n){ off[i0] = ex;      next[i0] = ex; }
  if (i1 < n){ off[i1] = ex + v0; next[i1] = ex + v0; }
  if (blockIdx.x == 0 && t == 0) off[n] = TOTAL;
}

// combined order-scatter (point slots then voxel slots)
__global__ void k_order2(const int* __restrict__ cin, const int* __restrict__ cil,
                         const int* __restrict__ inv, int* __restrict__ next,
                         int* __restrict__ pid, int* __restrict__ vsrc,
                         int* __restrict__ vid){
  int i = blockIdx.x * blockDim.x + threadIdx.x;
  if (i < NPTS){
    int s = cin[i];
    int idx = atomicAdd(&next[s], 1);
    pid[idx]  = i;
    vsrc[idx] = cil[i];
  } else if (i < TOTAL){
    int v = i - NPTS;
    int idx = atomicAdd(&next[NV2 + inv[v]], 1) - NPTS;
    vid[idx] = v;
  }
}

// ======== segmented mean -> output (atomic-free, unroll-2) ========

__global__ __launch_bounds__(256) void k_segmean_p(
    const float* __restrict__ z, const int* __restrict__ off,
    const int* __restrict__ pid, const int* __restrict__ vsrc,
    float* __restrict__ out){
  int s = blockIdx.x * 4 + (threadIdx.x >> 6);
  if (s >= NV2) return;
  int lane = threadIdx.x & 63;
  int start = off[s], end = off[s + 1];
  float2 a0 = make_float2(0.f, 0.f), a1 = make_float2(0.f, 0.f);
  int j = start;
  for (; j + 1 < end; j += 2){
    int v0 = vsrc[j], v1 = vsrc[j + 1];
    float2 x0 = *(const float2*)(z + (size_t)v0 * C + lane * 2);
    float2 x1 = *(const float2*)(z + (size_t)v1 * C + lane * 2);
    a0.x += x0.x; a0.y += x0.y;
    a1.x += x1.x; a1.y += x1.y;
  }
  if (j < end){
    int v0 = vsrc[j];
    float2 x0 = *(const float2*)(z + (size_t)v0 * C + lane * 2);
    a0.x += x0.x; a0.y += x0.y;
  }
  float invn = 1.f / (float)max(end - start, 1);
  float2 acc = make_float2((a0.x + a1.x) * invn, (a0.y + a1.y) * invn);
  for (int q = start; q < end; ++q){
    int p = pid[q];
    *(float2*)(out + (size_t)p * C + lane * 2) = acc;
  }
}

// ======== single-stage MFMA GEMM (step 5: t = hm @ Wo1_bot + bo1) ========
// A-frag: lane l holds A[m0+(l&15)][ks*32+(l>>4)*8 .. +7]
// D: col = nt*16+(l&15), row = m0+(l>>4)*4+reg   [m89-verified]
template<bool LRELU, bool BIAS>
__global__ __launch_bounds__(256) void k_mgemm(
    const float* __restrict__ A,
    const unsigned short* __restrict__ wh, const unsigned short* __restrict__ wl,
    const float* __restrict__ bias, float* __restrict__ out, int M)
{
  const int l  = threadIdx.x & 63;
  const int wv = threadIdx.x >> 6;
  const int m0 = blockIdx.x * 64 + wv * 16;
  if (m0 >= M) return;
  const int row = m0 + (l & 15);
  const int kb  = (l >> 4) * 8;

  bf16x8 ah[4], al[4];
  const float* ar = A + (size_t)row * 128;
  #pragma unroll
  for (int ks = 0; ks < 4; ++ks){
    float v[8];
    *(float4*)&v[0] = *(const float4*)(ar + ks * 32 + kb);
    *(float4*)&v[4] = *(const float4*)(ar + ks * 32 + kb + 4);
    split8(v, ah[ks], al[ks]);
  }

  const int colb  = l & 15;
  const int rbase = m0 + (l >> 4) * 4;

  #pragma unroll
  for (int nt = 0; nt < 8; ++nt){
    f32x4 acc = {0.f, 0.f, 0.f, 0.f};
    #pragma unroll
    for (int ks = 0; ks < 4; ++ks){
      const size_t fo = (size_t)((nt * 4 + ks) * 64 + l) * 8;
      bf16x8 bh = *(const bf16x8*)(wh + fo);
      bf16x8 bl = *(const bf16x8*)(wl + fo);
      acc = __builtin_amdgcn_mfma_f32_16x16x32_bf16(ah[ks], bh, acc, 0, 0, 0);
      acc = __builtin_amdgcn_mfma_f32_16x16x32_bf16(al[ks], bh, acc, 0, 0, 0);
      acc = __builtin_amdgcn_mfma_f32_16x16x32_bf16(ah[ks], bl, acc, 0, 0, 0);
    }
    const int col = nt * 16 + colb;
    float bc = 0.f;
    if constexpr (BIAS) bc = bias[col];
    #pragma unroll
    for (int r = 0; r < 4; ++r){
      float o = acc[r] + bc;
      if constexpr (LRELU) o = lrelu(o);
      out[(size_t)(rbase + r) * 128 + col] = o;
    }
  }
}

// ======== fused identity -> y -> z chain: 1 strip/wave, chunked LDS ========
// PINNED ALLOCATION: waves_per_eu(4,4) — r13's spill (VGPR=64, 193 µs) came
// from the allocator targeting 8 waves/SIMD under a min-only bound. min=max=4
// forces the 128-VGPR budget; r14 confirmed deterministic no-spill at 347 µs.
constexpr int CW = 36;   // chunk row stride (floats): 32 + 4 pad

__global__ __launch_bounds__(256)
__attribute__((amdgpu_waves_per_eu(4, 4)))
void k_fused3(
    const float* __restrict__ f, const float* __restrict__ vf,
    const unsigned short* __restrict__ wh1, const unsigned short* __restrict__ wl1,
    const unsigned short* __restrict__ wh2, const unsigned short* __restrict__ wl2,
    const unsigned short* __restrict__ wh3, const unsigned short* __restrict__ wl3,
    const float* __restrict__ b_in, const float* __restrict__ trow,
    const int* __restrict__ inv, const float* __restrict__ bo2,
    float* __restrict__ z, int M)
{
  __shared__ float chunk[4][2][16 * CW];       // 18 KB
  const int l  = threadIdx.x & 63;
  const int wv = threadIdx.x >> 6;
  const int m0 = blockIdx.x * 64 + wv * 16;
  if (m0 >= M) return;
  const int colb = l & 15;
  const int g    = l >> 4;
  const int rb   = m0 + g * 4;

  bf16x8 ahA[4], alA[4];   // current-stage fragments
  bf16x8 ahB[4], alB[4];   // next-stage fragments (built during current stage)

  // ---- stage-0 A frags from global: x = f + vf
  {
    const float* ar  = f  + (size_t)(m0 + colb) * 128;
    const float* ar2 = vf + (size_t)(m0 + colb) * 128;
    #pragma unroll
    for (int ks = 0; ks < 4; ++ks){
      float v[8], u[8];
      *(float4*)&v[0] = *(const float4*)(ar  + ks * 32 + g * 8);
      *(float4*)&v[4] = *(const float4*)(ar  + ks * 32 + g * 8 + 4);
      *(float4*)&u[0] = *(const float4*)(ar2 + ks * 32 + g * 8);
      *(float4*)&u[4] = *(const float4*)(ar2 + ks * 32 + g * 8 + 4);
      #pragma unroll
      for (int j = 0; j < 8; ++j) v[j] += u[j];
      split8(v, ahA[ks], alA[ks]);
    }
  }

  int rid[4];
  #pragma unroll
  for (int r = 0; r < 4; ++r) rid[r] = inv[rb + r];

  // MFMA for one nt from (WH,WL) using fragments AH/AL
  #define ACC_NT(WH, WL, AH, AL, NT, ACC)                                       \
    {                                                                           \
      _Pragma("unroll")                                                         \
      for (int kk = 0; kk < 4; ++kk){                                           \
        const size_t fo = (size_t)(((NT) * 4 + kk) * 64 + l) * 8;               \
        bf16x8 bh = *(const bf16x8*)((WH) + fo);                                \
        bf16x8 bl = *(const bf16x8*)((WL) + fo);                                \
        ACC = __builtin_amdgcn_mfma_f32_16x16x32_bf16((AH)[kk], bh, ACC, 0,0,0);\
        ACC = __builtin_amdgcn_mfma_f32_16x16x32_bf16((AL)[kk], bh, ACC, 0,0,0);\
        ACC = __builtin_amdgcn_mfma_f32_16x16x32_bf16((AH)[kk], bl, ACC, 0,0,0);\
      }                                                                         \
    }

  // one chunked stage: compute 8 nt with EPI(nt,r,accval) -> chunk -> AH_O/AL_O
  #define RUN_CHUNKED(WH, WL, AH_I, AL_I, AH_O, AL_O, EPI)                      \
    _Pragma("unroll")                                                           \
    for (int ks = 0; ks < 4; ++ks){                                             \
      float* Tc = &chunk[wv][ks & 1][0];                                        \
      _Pragma("unroll")                                                         \
      for (int h = 0; h < 2; ++h){                                              \
        const int nt = 2 * ks + h;                                              \
        f32x4 acc = {0.f, 0.f, 0.f, 0.f};                                       \
        ACC_NT(WH, WL, AH_I, AL_I, nt, acc);                                    \
        _Pragma("unroll")                                                       \
        for (int r = 0; r < 4; ++r){                                            \
          float o = EPI(nt, r, acc[r]);                                         \
          Tc[(g * 4 + r) * CW + h * 16 + colb] = o;                             \
        }                                                                       \
      }                                                                         \
      { float v[8];                                                             \
        *(float4*)&v[0] = *(const float4*)&Tc[colb * CW + g * 8];               \
        *(float4*)&v[4] = *(const float4*)&Tc[colb * CW + g * 8 + 4];           \
        split8(v, (AH_O)[ks], (AL_O)[ks]); }                                    \
    }

  // ---- stage 1: identity = lrelu(x @ W_in + b_in)      (A -> B)
  #define EPI1(NT, R, V) lrelu((V) + b_in[(NT) * 16 + colb])
  RUN_CHUNKED(wh1, wl1, ahA, alA, ahB, alB, EPI1);

  // ---- stage 2: y = lrelu(identity @ Wo1_top + t[inv]) (B -> A)
  #define EPI2(NT, R, V) lrelu((V) + trow[(size_t)rid[R] * 128 + (NT) * 16 + colb])
  RUN_CHUNKED(wh2, wl2, ahB, alB, ahA, alA, EPI2);

  // ---- stage 3: z = y @ Wo2 + bo2 -> global            (A -> out)
  #pragma unroll
  for (int nt = 0; nt < 8; ++nt){
    f32x4 acc = {0.f, 0.f, 0.f, 0.f};
    ACC_NT(wh3, wl3, ahA, alA, nt, acc);
    const int col = nt * 16 + colb;
    const float bc = bo2[col];
    #pragma unroll
    for (int r = 0; r < 4; ++r)
      z[(size_t)(rb + r) * 128 + col] = acc[r] + bc;
  }
  #undef ACC_NT
  #undef RUN_CHUNKED
  #undef EPI1
  #undef EPI2
}

// ======== f32 row-tiled GEMM for the ND-row BN stages ========
// GATHER: A-row = segment_mean over {f[v]+vf[v] : v in segment row} computed
// inline in the staging loop (fuses the old k_segmean_ds; deletes the ds_mean
// round-trip). off/vid per the combined scan (d-side biased by NPTS).
template<int K, int N, bool LRELU, bool STATS, bool BNPRE, bool BIAS, bool GATHER>
__global__ __launch_bounds__(256) void k_gemm(
    const float* __restrict__ A,
    const float* __restrict__ gf, const float* __restrict__ gvf,
    const int* __restrict__ goff, const int* __restrict__ gvid,
    const float* __restrict__ bnstats, const float* __restrict__ bng,
    const float* __restrict__ bnbeta, float bninvn,
    const float* __restrict__ W, const float* __restrict__ bias,
    float* __restrict__ out, float* __restrict__ stats, int M)
{
  constexpr int BM = 64;
  constexpr int G  = N / 4;
  constexpr int TY = 256 / G;
  constexpr int R  = BM / TY;
  constexpr int KV = K / 4;

  __shared__ float At[K][BM + 4];
  __shared__ float red[STATS ? 2 * TY * N : 1];

  const int tid  = threadIdx.x;
  const int tx   = tid % G;
  const int ty   = tid / G;
  const int row0 = blockIdx.x * BM;

  for (int i = tid; i < BM * KV; i += 256){
    int r  = i / KV;
    int kc = (i % KV) * 4;
    int row = row0 + r;
    float v[4] = {0.f, 0.f, 0.f, 0.f};
    if (row < M){
      if constexpr (GATHER){
        int s0 = goff[NV2 + row] - NPTS, e0 = goff[NV2 + row + 1] - NPTS;
        for (int j = s0; j < e0; ++j){
          int vv = gvid[j];
          float4 a = *(const float4*)(gf  + (size_t)vv * C + kc);
          float4 b = *(const float4*)(gvf + (size_t)vv * C + kc);
          v[0] += a.x + b.x; v[1] += a.y + b.y;
          v[2] += a.z + b.z; v[3] += a.w + b.w;
        }
        float invn = 1.f / (float)max(e0 - s0, 1);
        v[0] *= invn; v[1] *= invn; v[2] *= invn; v[3] *= invn;
      } else {
        *(float4*)v = *(const float4*)(A + (size_t)row * K + kc);
        if constexpr (BNPRE){
          #pragma unroll
          for (int q = 0; q < 4; ++q){
            int c = kc + q;
            float mean = bnstats[c] * bninvn;
            float var  = bnstats[K + c] * bninvn - mean * mean;
            float sc   = bng[c] * rsqrtf(var + 1e-5f);
            float sh   = bnbeta[c] - mean * sc;
            v[q] = v[q] * sc + sh;
          }
        }
      }
    }
    At[kc + 0][r] = v[0]; At[kc + 1][r] = v[1];
    At[kc + 2][r] = v[2]; At[kc + 3][r] = v[3];
  }
  __syncthreads();

  float acc[R][4];
  #pragma unroll
  for (int r = 0; r < R; ++r)
    for (int j = 0; j < 4; ++j) acc[r][j] = 0.f;

  #pragma unroll 4
  for (int k = 0; k < K; ++k){
    float4 w4 = *(const float4*)(W + (size_t)k * N + tx * 4);
    const float4* ap = (const float4*)&At[k][ty * R];
    #pragma unroll
    for (int rq = 0; rq < R / 4; ++rq){
      float4 a4 = ap[rq];
      float av[4] = {a4.x, a4.y, a4.z, a4.w};
      #pragma unroll
      for (int rr = 0; rr < 4; ++rr){
        int r = rq * 4 + rr;
        acc[r][0] += av[rr] * w4.x;
        acc[r][1] += av[rr] * w4.y;
        acc[r][2] += av[rr] * w4.z;
        acc[r][3] += av[rr] * w4.w;
      }
    }
  }

  float bx[4] = {0.f, 0.f, 0.f, 0.f};
  if constexpr (BIAS){
    float4 b = *(const float4*)(bias + tx * 4);
    bx[0] = b.x; bx[1] = b.y; bx[2] = b.z; bx[3] = b.w;
  }

  float ps[4] = {0.f,0.f,0.f,0.f}, pq[4] = {0.f,0.f,0.f,0.f};
  #pragma unroll
  for (int r = 0; r < R; ++r){
    int row = row0 + ty * R + r;
    if (row < M){
      float o[4];
      #pragma unroll
      for (int j = 0; j < 4; ++j) o[j] = acc[r][j] + bx[j];
      if constexpr (LRELU){
        #pragma unroll
        for (int j = 0; j < 4; ++j) o[j] = lrelu(o[j]);
      }
      *(float4*)(out + (size_t)row * N + tx * 4) = make_float4(o[0], o[1], o[2], o[3]);
      if constexpr (STATS){
        #pragma unroll
        for (int j = 0; j < 4; ++j){ ps[j] += o[j]; pq[j] += o[j] * o[j]; }
      }
    }
  }

  if constexpr (STATS){
    #pragma unroll
    for (int j = 0; j < 4; ++j){
      red[(0 * TY + ty) * N + tx * 4 + j] = ps[j];
      red[(1 * TY + ty) * N + tx * 4 + j] = pq[j];
    }
    __syncthreads();
    for (int col = tid; col < N; col += 256){
      float s = 0.f, q = 0.f;
      #pragma unroll
      for (int t2 = 0; t2 < TY; ++t2){
        s += red[(0 * TY + t2) * N + col];
        q += red[(1 * TY + t2) * N + col];
      }
      atomicAdd(&stats[col], s);
      atomicAdd(&stats[N + col], q);
    }
  }
}

inline int cdiv(int a, int b){ return (a + b - 1) / b; }

} // namespace

extern "C" void kernel_launch(void* const* d_in, const int* in_sizes, int n_in,
                              void* d_out, int out_size, void* d_ws, size_t ws_size,
                              hipStream_t stream){
  const float* features = (const float*)d_in[0];
  const float* v_fea    = (const float*)d_in[1];
  const int*   inv      = (const int*)d_in[2];
  const int*   cil      = (const int*)d_in[3];
  const int*   cin      = (const int*)d_in[4];
  const float* W_in  = (const float*)d_in[5];
  const float* b_in  = (const float*)d_in[6];
  const float* W1    = (const float*)d_in[7];
  const float* b1    = (const float*)d_in[8];
  const float* g1    = (const float*)d_in[9];
  const float* beta1 = (const float*)d_in[10];
  const float* W2    = (const float*)d_in[11];
  const float* b2    = (const float*)d_in[12];
  const float* g2    = (const float*)d_in[13];
  const float* beta2 = (const float*)d_in[14];
  const float* W3    = (const float*)d_in[15];
  const float* b3    = (const float*)d_in[16];
  const float* Wo1   = (const float*)d_in[17];
  const float* bo1   = (const float*)d_in[18];
  const float* Wo2   = (const float*)d_in[19];
  const float* bo2   = (const float*)d_in[20];

  // ---- workspace layout ----
  float* ws = (float*)d_ws;
  float* tbuf    = ws;                               // ND*C (t)
  float* h1      = tbuf + (size_t)ND * C;            // ND*64
  float* h2      = h1 + (size_t)ND * 64;             // ND*64
  float* big     = h2 + (size_t)ND * 64;             // NV*C: hm -> z
  int*   histc   = (int*)(big + (size_t)NV * C);     // NSEG
  float* stats   = (float*)(histc + NSEG);           // 512 (zeroed with histc)
  int*   off     = (int*)(stats + 512);              // NSEG+1
  int*   next    = off + NSEG + 1;                   // NSEG
  int*   tsum    = next + NSEG;                      // scan tiles (<=256)
  int*   pid     = tsum + 256;                       // NPTS
  int*   vsrc    = pid + NPTS;                       // NPTS
  int*   vid     = vsrc + NPTS;                      // NV
  // packed weights (16B-aligned): [w][hi|lo], w = Win,Wo1t,Wo1b,Wo2
  unsigned short* pw =
      (unsigned short*)((((uintptr_t)(vid + NV)) + 15) & ~(uintptr_t)15);
  unsigned short* Win_h  = pw;
  unsigned short* Win_l  = pw + 16384;
  unsigned short* Wo1t_h = pw + 32768;
  unsigned short* Wo1t_l = pw + 49152;
  unsigned short* Wo1b_h = pw + 65536;
  unsigned short* Wo1b_l = pw + 81920;
  unsigned short* Wo2_h  = pw + 98304;
  unsigned short* Wo2_l  = pw + 114688;

  float* t      = tbuf;
  float* stats1 = stats;          // sum[64] | sq[64]
  float* stats2 = stats + 128;    // sum[64] | sq[64]

  const int NT = cdiv(NSEG, ST);   // 176 scan tiles

  // one memset: combined histogram + BN stat sums (adjacent)
  hipMemsetAsync(histc, 0, (size_t)(NSEG + 512) * sizeof(int), stream);

  // pack weights (blocks 0..31) + combined histogram (rest)
  k_setup<<<32 + cdiv(TOTAL, 256), 256, 0, stream>>>(
      W_in, Wo1, Wo1 + (size_t)C * C, Wo2, pw, cin, inv, histc);

  // hierarchical scan + order-scatter
  k_tilesum<<<NT, 256, 0, stream>>>(histc, NSEG, tsum);
  k_scantiles<<<1, 256, 0, stream>>>(tsum, NT);
  k_scanwrite<<<NT, 256, 0, stream>>>(histc, tsum, NSEG, off, next);
  k_order2<<<cdiv(TOTAL, 256), 256, 0, stream>>>(cin, cil, inv, next, pid, vsrc, vid);

  // 1+2) h1 = lrelu(segment_mean(features+v_fea, inv) @ W1 + b1), BN1 stats
  //      (segment mean gathered inline in the A-staging loop)
  k_gemm<128, 64, true, true, false, true, true>
      <<<cdiv(ND, 64), 256, 0, stream>>>(nullptr, features, v_fea, off, vid,
                                          nullptr, nullptr, nullptr, 0.f,
                                          W1, b1, h1, stats1, ND);

  // 3) h2 = lrelu(bn1(h1) @ W2 + b2), BN2 stats   (BN1 folded into prologue)
  k_gemm<64, 64, true, true, true, true, false>
      <<<cdiv(ND, 64), 256, 0, stream>>>(h1, nullptr, nullptr, nullptr, nullptr,
                                          stats1, g1, beta1, 1.f / ND,
                                          W2, b2, h2, stats2, ND);

  // 4) hm = lrelu(bn2(h2) @ W3 + b3) -> big       (BN2 folded into prologue)
  k_gemm<64, 128, true, false, true, true, false>
      <<<cdiv(ND, 64), 256, 0, stream>>>(h2, nullptr, nullptr, nullptr, nullptr,
                                          stats2, g2, beta2, 1.f / ND,
                                          W3, b3, big, nullptr, ND);

  // 5) t = hm @ Wo1_bot + bo1                     (MFMA)
  k_mgemm<false, true><<<cdiv(ND, 64), 256, 0, stream>>>(
      big, Wo1b_h, Wo1b_l, bo1, t, ND);

  // 6-8) fused 1-strip chunked, pinned waves_per_eu(4,4)
  k_fused3<<<cdiv(NV, 64), 256, 0, stream>>>(
      features, v_fea, Win_h, Win_l, Wo1t_h, Wo1t_l, Wo2_h, Wo2_l,
      b_in, t, inv, bo2, big, NV);

  // 9) fused segment-mean -> output
  k_segmean_p<<<cdiv(NV2, 4), 256, 0, stream>>>(big, off, pid, vsrc, (float*)d_out);

  (void)in_sizes; (void)n_in; (void)out_size; (void)ws_size;
}

// Round 16
// 344.846 us; speedup vs baseline: 1.0181x; 1.0181x over previous
//
#include <hip/hip_runtime.h>

#define DEVI static __device__ __forceinline__

namespace {

constexpr int NV   = 120000;
constexpr int ND   = 30000;
constexpr int NV2  = 60000;
constexpr int NPTS = 400000;
constexpr int C    = 128;

constexpr int NSEG  = NV2 + ND;        // combined histogram length (90000)
constexpr int TOTAL = NPTS + NV;       // combined scan total
constexpr int ST    = 512;             // scan tile (elements per block)

typedef __attribute__((ext_vector_type(8))) short bf16x8;   // 8 bf16 = 4 VGPR
typedef __attribute__((ext_vector_type(4))) float f32x4;    // MFMA accumulator

DEVI float lrelu(float x){ return x > 0.f ? x : 0.1f*x; }

DEVI unsigned short f2bf(float f){            // f32 -> bf16 RNE
  unsigned u = __float_as_uint(f);
  return (unsigned short)((u + 0x7FFFu + ((u >> 16) & 1u)) >> 16);
}
DEVI float bf2f(unsigned short h){ return __uint_as_float((unsigned)h << 16); }

DEVI void split8(const float* v, bf16x8& h, bf16x8& lo){
  #pragma unroll
  for (int j = 0; j < 8; ++j){
    unsigned short hb = f2bf(v[j]);
    h[j]  = (short)hb;
    lo[j] = (short)f2bf(v[j] - bf2f(hb));
  }
}

// ======== setup: weight pack (blocks 0..31) + combined histogram (rest) ====
// pw layout: [w][hi 16384 | lo 16384], w = Win, Wo1t, Wo1b, Wo2.
// B-frag order: frag=(nt*4+ks)*64+lane holds B[k][n]: n=nt*16+(lane&15),
// k=ks*32+(lane>>4)*8+j.
__global__ void k_setup(const float* __restrict__ W0, const float* __restrict__ W1,
                        const float* __restrict__ W2, const float* __restrict__ W3,
                        unsigned short* __restrict__ pw,
                        const int* __restrict__ cin, const int* __restrict__ inv,
                        int* __restrict__ histc){
  int bid = blockIdx.x;
  if (bid < 32){
    int w = bid >> 3;
    const float* W = (w == 0) ? W0 : (w == 1) ? W1 : (w == 2) ? W2 : W3;
    unsigned short* ph = pw + (size_t)w * 32768;
    unsigned short* pl = ph + 16384;
    int frag = (bid & 7) * 256 + threadIdx.x;
    int lane = frag & 63;
    int ks = (frag >> 6) & 3;
    int nt = frag >> 8;
    int n  = nt * 16 + (lane & 15);
    int k0 = ks * 32 + (lane >> 4) * 8;
    int ob = frag * 8;
    #pragma unroll
    for (int j = 0; j < 8; ++j){
      float w_ = W[(size_t)(k0 + j) * 128 + n];
      unsigned short hi = f2bf(w_);
      ph[ob + j] = hi;
      pl[ob + j] = f2bf(w_ - bf2f(hi));
    }
  } else {
    int i = (bid - 32) * 256 + threadIdx.x;
    if (i < NPTS) atomicAdd(&histc[cin[i]], 1);
    else if (i < TOTAL) atomicAdd(&histc[NV2 + inv[i - NPTS]], 1);
  }
}

// ======== hierarchical scan (3-pass; r10-proven) ========

__global__ __launch_bounds__(256) void k_tilesum(const int* __restrict__ h, int n,
                                                 int* __restrict__ ts){
  __shared__ int red[256];
  int base = blockIdx.x * ST;
  int t = threadIdx.x;
  int a0 = base + t, a1 = base + t + 256;
  red[t] = (a0 < n ? h[a0] : 0) + (a1 < n ? h[a1] : 0);
  __syncthreads();
  for (int d = 128; d > 0; d >>= 1){
    if (t < d) red[t] += red[t + d];
    __syncthreads();
  }
  if (t == 0) ts[blockIdx.x] = red[0];
}

__global__ __launch_bounds__(256) void k_scantiles(int* __restrict__ ts, int nt){
  __shared__ int ls[256];
  int t = threadIdx.x;
  ls[t] = t < nt ? ts[t] : 0;
  __syncthreads();
  for (int d = 1; d < 256; d <<= 1){
    int v = t >= d ? ls[t - d] : 0;
    __syncthreads();
    ls[t] += v;
    __syncthreads();
  }
  if (t < nt) ts[t] = (t == 0) ? 0 : ls[t - 1];
}

__global__ __launch_bounds__(256) void k_scanwrite(
    const int* __restrict__ h, const int* __restrict__ ts, int n,
    int* __restrict__ off, int* __restrict__ next){
  __shared__ int ls[256];
  int base = blockIdx.x * ST;
  int t = threadIdx.x;
  int i0 = base + 2 * t, i1 = i0 + 1;
  int v0 = (i0 < n) ? h[i0] : 0;
  int v1 = (i1 < n) ? h[i1] : 0;
  ls[t] = v0 + v1;
  __syncthreads();
  for (int d = 1; d < 256; d <<= 1){
    int v = t >= d ? ls[t - d] : 0;
    __syncthreads();
    ls[t] += v;
    __syncthreads();
  }
  int ex = ts[blockIdx.x] + ((t == 0) ? 0 : ls[t - 1]);
  if (i0 < n){ off[i0] = ex;      next[i0] = ex; }
  if (i1 < n){ off[i1] = ex + v0; next[i1] = ex + v0; }
  if (blockIdx.x == 0 && t == 0) off[n] = TOTAL;
}

// combined order-scatter (point slots then voxel slots)
__global__ void k_order2(const int* __restrict__ cin, const int* __restrict__ cil,
                         const int* __restrict__ inv, int* __restrict__ next,
                         int* __restrict__ pid, int* __restrict__ vsrc,
                         int* __restrict__ vid){
  int i = blockIdx.x * blockDim.x + threadIdx.x;
  if (i < NPTS){
    int s = cin[i];
    int idx = atomicAdd(&next[s], 1);
    pid[idx]  = i;
    vsrc[idx] = cil[i];
  } else if (i < TOTAL){
    int v = i - NPTS;
    int idx = atomicAdd(&next[NV2 + inv[v]], 1) - NPTS;
    vid[idx] = v;
  }
}

// ======== segmented means (atomic-free, unroll-2) ========

__global__ __launch_bounds__(256) void k_segmean_ds(
    const float* __restrict__ f, const float* __restrict__ vf,
    const int* __restrict__ off, const int* __restrict__ vid,
    float* __restrict__ ds_mean){
  int s = blockIdx.x * 4 + (threadIdx.x >> 6);
  if (s >= ND) return;
  int lane = threadIdx.x & 63;
  int start = off[NV2 + s] - NPTS, end = off[NV2 + s + 1] - NPTS;
  float2 a0 = make_float2(0.f, 0.f), a1 = make_float2(0.f, 0.f);
  int j = start;
  for (; j + 1 < end; j += 2){
    int v0 = vid[j], v1 = vid[j + 1];
    float2 x0 = *(const float2*)(f  + (size_t)v0 * C + lane * 2);
    float2 y0 = *(const float2*)(vf + (size_t)v0 * C + lane * 2);
    float2 x1 = *(const float2*)(f  + (size_t)v1 * C + lane * 2);
    float2 y1 = *(const float2*)(vf + (size_t)v1 * C + lane * 2);
    a0.x += x0.x + y0.x; a0.y += x0.y + y0.y;
    a1.x += x1.x + y1.x; a1.y += x1.y + y1.y;
  }
  if (j < end){
    int v0 = vid[j];
    float2 x0 = *(const float2*)(f  + (size_t)v0 * C + lane * 2);
    float2 y0 = *(const float2*)(vf + (size_t)v0 * C + lane * 2);
    a0.x += x0.x + y0.x; a0.y += x0.y + y0.y;
  }
  float invn = 1.f / (float)max(end - start, 1);
  float2 acc = make_float2((a0.x + a1.x) * invn, (a0.y + a1.y) * invn);
  *(float2*)(ds_mean + (size_t)s * C + lane * 2) = acc;
}

__global__ __launch_bounds__(256) void k_segmean_p(
    const float* __restrict__ z, const int* __restrict__ off,
    const int* __restrict__ pid, const int* __restrict__ vsrc,
    float* __restrict__ out){
  int s = blockIdx.x * 4 + (threadIdx.x >> 6);
  if (s >= NV2) return;
  int lane = threadIdx.x & 63;
  int start = off[s], end = off[s + 1];
  float2 a0 = make_float2(0.f, 0.f), a1 = make_float2(0.f, 0.f);
  int j = start;
  for (; j + 1 < end; j += 2){
    int v0 = vsrc[j], v1 = vsrc[j + 1];
    float2 x0 = *(const float2*)(z + (size_t)v0 * C + lane * 2);
    float2 x1 = *(const float2*)(z + (size_t)v1 * C + lane * 2);
    a0.x += x0.x; a0.y += x0.y;
    a1.x += x1.x; a1.y += x1.y;
  }
  if (j < end){
    int v0 = vsrc[j];
    float2 x0 = *(const float2*)(z + (size_t)v0 * C + lane * 2);
    a0.x += x0.x; a0.y += x0.y;
  }
  float invn = 1.f / (float)max(end - start, 1);
  float2 acc = make_float2((a0.x + a1.x) * invn, (a0.y + a1.y) * invn);
  for (int q = start; q < end; ++q){
    int p = pid[q];
    *(float2*)(out + (size_t)p * C + lane * 2) = acc;
  }
}

// ======== single-stage MFMA GEMM (step 5: t = hm @ Wo1_bot + bo1) ========
// A-frag: lane l holds A[m0+(l&15)][ks*32+(l>>4)*8 .. +7]
// D: col = nt*16+(l&15), row = m0+(l>>4)*4+reg   [m89-verified]
template<bool LRELU, bool BIAS>
__global__ __launch_bounds__(256) void k_mgemm(
    const float* __restrict__ A,
    const unsigned short* __restrict__ wh, const unsigned short* __restrict__ wl,
    const float* __restrict__ bias, float* __restrict__ out, int M)
{
  const int l  = threadIdx.x & 63;
  const int wv = threadIdx.x >> 6;
  const int m0 = blockIdx.x * 64 + wv * 16;
  if (m0 >= M) return;
  const int row = m0 + (l & 15);
  const int kb  = (l >> 4) * 8;

  bf16x8 ah[4], al[4];
  const float* ar = A + (size_t)row * 128;
  #pragma unroll
  for (int ks = 0; ks < 4; ++ks){
    float v[8];
    *(float4*)&v[0] = *(const float4*)(ar + ks * 32 + kb);
    *(float4*)&v[4] = *(const float4*)(ar + ks * 32 + kb + 4);
    split8(v, ah[ks], al[ks]);
  }

  const int colb  = l & 15;
  const int rbase = m0 + (l >> 4) * 4;

  #pragma unroll
  for (int nt = 0; nt < 8; ++nt){
    f32x4 acc = {0.f, 0.f, 0.f, 0.f};
    #pragma unroll
    for (int ks = 0; ks < 4; ++ks){
      const size_t fo = (size_t)((nt * 4 + ks) * 64 + l) * 8;
      bf16x8 bh = *(const bf16x8*)(wh + fo);
      bf16x8 bl = *(const bf16x8*)(wl + fo);
      acc = __builtin_amdgcn_mfma_f32_16x16x32_bf16(ah[ks], bh, acc, 0, 0, 0);
      acc = __builtin_amdgcn_mfma_f32_16x16x32_bf16(al[ks], bh, acc, 0, 0, 0);
      acc = __builtin_amdgcn_mfma_f32_16x16x32_bf16(ah[ks], bl, acc, 0, 0, 0);
    }
    const int col = nt * 16 + colb;
    float bc = 0.f;
    if constexpr (BIAS) bc = bias[col];
    #pragma unroll
    for (int r = 0; r < 4; ++r){
      float o = acc[r] + bc;
      if constexpr (LRELU) o = lrelu(o);
      out[(size_t)(rbase + r) * 128 + col] = o;
    }
  }
}

// ======== fused identity -> y -> z chain: 1 strip/wave, chunked LDS ========
// PINNED ALLOCATION: waves_per_eu(4,4) — r13's spill (VGPR=64, 193 µs) came
// from the allocator targeting 8 waves/SIMD under a min-only bound. min=max=4
// forces the 128-VGPR budget; r14 confirmed deterministic no-spill at 347 µs.
constexpr int CW = 36;   // chunk row stride (floats): 32 + 4 pad

__global__ __launch_bounds__(256)
__attribute__((amdgpu_waves_per_eu(4, 4)))
void k_fused3(
    const float* __restrict__ f, const float* __restrict__ vf,
    const unsigned short* __restrict__ wh1, const unsigned short* __restrict__ wl1,
    const unsigned short* __restrict__ wh2, const unsigned short* __restrict__ wl2,
    const unsigned short* __restrict__ wh3, const unsigned short* __restrict__ wl3,
    const float* __restrict__ b_in, const float* __restrict__ trow,
    const int* __restrict__ inv, const float* __restrict__ bo2,
    float* __restrict__ z, int M)
{
  __shared__ float chunk[4][2][16 * CW];       // 18 KB
  const int l  = threadIdx.x & 63;
  const int wv = threadIdx.x >> 6;
  const int m0 = blockIdx.x * 64 + wv * 16;
  if (m0 >= M) return;
  const int colb = l & 15;
  const int g    = l >> 4;
  const int rb   = m0 + g * 4;

  bf16x8 ahA[4], alA[4];   // current-stage fragments
  bf16x8 ahB[4], alB[4];   // next-stage fragments (built during current stage)

  // ---- stage-0 A frags from global: x = f + vf
  {
    const float* ar  = f  + (size_t)(m0 + colb) * 128;
    const float* ar2 = vf + (size_t)(m0 + colb) * 128;
    #pragma unroll
    for (int ks = 0; ks < 4; ++ks){
      float v[8], u[8];
      *(float4*)&v[0] = *(const float4*)(ar  + ks * 32 + g * 8);
      *(float4*)&v[4] = *(const float4*)(ar  + ks * 32 + g * 8 + 4);
      *(float4*)&u[0] = *(const float4*)(ar2 + ks * 32 + g * 8);
      *(float4*)&u[4] = *(const float4*)(ar2 + ks * 32 + g * 8 + 4);
      #pragma unroll
      for (int j = 0; j < 8; ++j) v[j] += u[j];
      split8(v, ahA[ks], alA[ks]);
    }
  }

  int rid[4];
  #pragma unroll
  for (int r = 0; r < 4; ++r) rid[r] = inv[rb + r];

  // MFMA for one nt from (WH,WL) using fragments AH/AL
  #define ACC_NT(WH, WL, AH, AL, NT, ACC)                                       \
    {                                                                           \
      _Pragma("unroll")                                                         \
      for (int kk = 0; kk < 4; ++kk){                                           \
        const size_t fo = (size_t)(((NT) * 4 + kk) * 64 + l) * 8;               \
        bf16x8 bh = *(const bf16x8*)((WH) + fo);                                \
        bf16x8 bl = *(const bf16x8*)((WL) + fo);                                \
        ACC = __builtin_amdgcn_mfma_f32_16x16x32_bf16((AH)[kk], bh, ACC, 0,0,0);\
        ACC = __builtin_amdgcn_mfma_f32_16x16x32_bf16((AL)[kk], bh, ACC, 0,0,0);\
        ACC = __builtin_amdgcn_mfma_f32_16x16x32_bf16((AH)[kk], bl, ACC, 0,0,0);\
      }                                                                         \
    }

  // one chunked stage: compute 8 nt with EPI(nt,r,accval) -> chunk -> AH_O/AL_O
  #define RUN_CHUNKED(WH, WL, AH_I, AL_I, AH_O, AL_O, EPI)                      \
    _Pragma("unroll")                                                           \
    for (int ks = 0; ks < 4; ++ks){                                             \
      float* Tc = &chunk[wv][ks & 1][0];                                        \
      _Pragma("unroll")                                                         \
      for (int h = 0; h < 2; ++h){                                              \
        const int nt = 2 * ks + h;                                              \
        f32x4 acc = {0.f, 0.f, 0.f, 0.f};                                       \
        ACC_NT(WH, WL, AH_I, AL_I, nt, acc);                                    \
        _Pragma("unroll")                                                       \
        for (int r = 0; r < 4; ++r){                                            \
          float o = EPI(nt, r, acc[r]);                                         \
          Tc[(g * 4 + r) * CW + h * 16 + colb] = o;                             \
        }                                                                       \
      }                                                                         \
      { float v[8];                                                             \
        *(float4*)&v[0] = *(const float4*)&Tc[colb * CW + g * 8];               \
        *(float4*)&v[4] = *(const float4*)&Tc[colb * CW + g * 8 + 4];           \
        split8(v, (AH_O)[ks], (AL_O)[ks]); }                                    \
    }

  // ---- stage 1: identity = lrelu(x @ W_in + b_in)      (A -> B)
  #define EPI1(NT, R, V) lrelu((V) + b_in[(NT) * 16 + colb])
  RUN_CHUNKED(wh1, wl1, ahA, alA, ahB, alB, EPI1);

  // ---- stage 2: y = lrelu(identity @ Wo1_top + t[inv]) (B -> A)
  #define EPI2(NT, R, V) lrelu((V) + trow[(size_t)rid[R] * 128 + (NT) * 16 + colb])
  RUN_CHUNKED(wh2, wl2, ahB, alB, ahA, alA, EPI2);

  // ---- stage 3: z = y @ Wo2 + bo2 -> global            (A -> out)
  #pragma unroll
  for (int nt = 0; nt < 8; ++nt){
    f32x4 acc = {0.f, 0.f, 0.f, 0.f};
    ACC_NT(wh3, wl3, ahA, alA, nt, acc);
    const int col = nt * 16 + colb;
    const float bc = bo2[col];
    #pragma unroll
    for (int r = 0; r < 4; ++r)
      z[(size_t)(rb + r) * 128 + col] = acc[r] + bc;
  }
  #undef ACC_NT
  #undef RUN_CHUNKED
  #undef EPI1
  #undef EPI2
}

// ======== f32 row-tiled GEMM for the ND-row BN stages (BN folded in) ========
template<int K, int N, bool LRELU, bool STATS, bool BNPRE, bool BIAS>
__global__ __launch_bounds__(256) void k_gemm(
    const float* __restrict__ A,
    const float* __restrict__ bnstats, const float* __restrict__ bng,
    const float* __restrict__ bnbeta, float bninvn,
    const float* __restrict__ W, const float* __restrict__ bias,
    float* __restrict__ out, float* __restrict__ stats, int M)
{
  constexpr int BM = 64;
  constexpr int G  = N / 4;
  constexpr int TY = 256 / G;
  constexpr int R  = BM / TY;
  constexpr int KV = K / 4;

  __shared__ float At[K][BM + 4];
  __shared__ float red[STATS ? 2 * TY * N : 1];

  const int tid  = threadIdx.x;
  const int tx   = tid % G;
  const int ty   = tid / G;
  const int row0 = blockIdx.x * BM;

  for (int i = tid; i < BM * KV; i += 256){
    int r  = i / KV;
    int kc = (i % KV) * 4;
    int row = row0 + r;
    float v[4] = {0.f, 0.f, 0.f, 0.f};
    if (row < M){
      *(float4*)v = *(const float4*)(A + (size_t)row * K + kc);
      if constexpr (BNPRE){
        #pragma unroll
        for (int q = 0; q < 4; ++q){
          int c = kc + q;
          float mean = bnstats[c] * bninvn;
          float var  = bnstats[K + c] * bninvn - mean * mean;
          float sc   = bng[c] * rsqrtf(var + 1e-5f);
          float sh   = bnbeta[c] - mean * sc;
          v[q] = v[q] * sc + sh;
        }
      }
    }
    At[kc + 0][r] = v[0]; At[kc + 1][r] = v[1];
    At[kc + 2][r] = v[2]; At[kc + 3][r] = v[3];
  }
  __syncthreads();

  float acc[R][4];
  #pragma unroll
  for (int r = 0; r < R; ++r)
    for (int j = 0; j < 4; ++j) acc[r][j] = 0.f;

  #pragma unroll 4
  for (int k = 0; k < K; ++k){
    float4 w4 = *(const float4*)(W + (size_t)k * N + tx * 4);
    const float4* ap = (const float4*)&At[k][ty * R];
    #pragma unroll
    for (int rq = 0; rq < R / 4; ++rq){
      float4 a4 = ap[rq];
      float av[4] = {a4.x, a4.y, a4.z, a4.w};
      #pragma unroll
      for (int rr = 0; rr < 4; ++rr){
        int r = rq * 4 + rr;
        acc[r][0] += av[rr] * w4.x;
        acc[r][1] += av[rr] * w4.y;
        acc[r][2] += av[rr] * w4.z;
        acc[r][3] += av[rr] * w4.w;
      }
    }
  }

  float bx[4] = {0.f, 0.f, 0.f, 0.f};
  if constexpr (BIAS){
    float4 b = *(const float4*)(bias + tx * 4);
    bx[0] = b.x; bx[1] = b.y; bx[2] = b.z; bx[3] = b.w;
  }

  float ps[4] = {0.f,0.f,0.f,0.f}, pq[4] = {0.f,0.f,0.f,0.f};
  #pragma unroll
  for (int r = 0; r < R; ++r){
    int row = row0 + ty * R + r;
    if (row < M){
      float o[4];
      #pragma unroll
      for (int j = 0; j < 4; ++j) o[j] = acc[r][j] + bx[j];
      if constexpr (LRELU){
        #pragma unroll
        for (int j = 0; j < 4; ++j) o[j] = lrelu(o[j]);
      }
      *(float4*)(out + (size_t)row * N + tx * 4) = make_float4(o[0], o[1], o[2], o[3]);
      if constexpr (STATS){
        #pragma unroll
        for (int j = 0; j < 4; ++j){ ps[j] += o[j]; pq[j] += o[j] * o[j]; }
      }
    }
  }

  if constexpr (STATS){
    #pragma unroll
    for (int j = 0; j < 4; ++j){
      red[(0 * TY + ty) * N + tx * 4 + j] = ps[j];
      red[(1 * TY + ty) * N + tx * 4 + j] = pq[j];
    }
    __syncthreads();
    for (int col = tid; col < N; col += 256){
      float s = 0.f, q = 0.f;
      #pragma unroll
      for (int t2 = 0; t2 < TY; ++t2){
        s += red[(0 * TY + t2) * N + col];
        q += red[(1 * TY + t2) * N + col];
      }
      atomicAdd(&stats[col], s);
      atomicAdd(&stats[N + col], q);
    }
  }
}

inline int cdiv(int a, int b){ return (a + b - 1) / b; }

} // namespace

extern "C" void kernel_launch(void* const* d_in, const int* in_sizes, int n_in,
                              void* d_out, int out_size, void* d_ws, size_t ws_size,
                              hipStream_t stream){
  const float* features = (const float*)d_in[0];
  const float* v_fea    = (const float*)d_in[1];
  const int*   inv      = (const int*)d_in[2];
  const int*   cil      = (const int*)d_in[3];
  const int*   cin      = (const int*)d_in[4];
  const float* W_in  = (const float*)d_in[5];
  const float* b_in  = (const float*)d_in[6];
  const float* W1    = (const float*)d_in[7];
  const float* b1    = (const float*)d_in[8];
  const float* g1    = (const float*)d_in[9];
  const float* beta1 = (const float*)d_in[10];
  const float* W2    = (const float*)d_in[11];
  const float* b2    = (const float*)d_in[12];
  const float* g2    = (const float*)d_in[13];
  const float* beta2 = (const float*)d_in[14];
  const float* W3    = (const float*)d_in[15];
  const float* b3    = (const float*)d_in[16];
  const float* Wo1   = (const float*)d_in[17];
  const float* bo1   = (const float*)d_in[18];
  const float* Wo2   = (const float*)d_in[19];
  const float* bo2   = (const float*)d_in[20];

  // ---- workspace layout ----
  float* ws = (float*)d_ws;
  float* ds_mean = ws;                               // ND*C (t aliases later)
  float* h1      = ds_mean + (size_t)ND * C;         // ND*64
  float* h2      = h1 + (size_t)ND * 64;             // ND*64
  float* big     = h2 + (size_t)ND * 64;             // NV*C: hm -> z
  int*   histc   = (int*)(big + (size_t)NV * C);     // NSEG
  float* stats   = (float*)(histc + NSEG);           // 512 (zeroed with histc)
  int*   off     = (int*)(stats + 512);              // NSEG+1
  int*   next    = off + NSEG + 1;                   // NSEG
  int*   tsum    = next + NSEG;                      // scan tiles (<=256)
  int*   pid     = tsum + 256;                       // NPTS
  int*   vsrc    = pid + NPTS;                       // NPTS
  int*   vid     = vsrc + NPTS;                      // NV
  // packed weights (16B-aligned): [w][hi|lo], w = Win,Wo1t,Wo1b,Wo2
  unsigned short* pw =
      (unsigned short*)((((uintptr_t)(vid + NV)) + 15) & ~(uintptr_t)15);
  unsigned short* Win_h  = pw;
  unsigned short* Win_l  = pw + 16384;
  unsigned short* Wo1t_h = pw + 32768;
  unsigned short* Wo1t_l = pw + 49152;
  unsigned short* Wo1b_h = pw + 65536;
  unsigned short* Wo1b_l = pw + 81920;
  unsigned short* Wo2_h  = pw + 98304;
  unsigned short* Wo2_l  = pw + 114688;

  float* t      = ds_mean;        // alias: ds_mean dead after step 2
  float* stats1 = stats;          // sum[64] | sq[64]
  float* stats2 = stats + 128;    // sum[64] | sq[64]

  const int NT = cdiv(NSEG, ST);   // 176 scan tiles

  // one memset: combined histogram + BN stat sums (adjacent)
  hipMemsetAsync(histc, 0, (size_t)(NSEG + 512) * sizeof(int), stream);

  // pack weights (blocks 0..31) + combined histogram (rest)
  k_setup<<<32 + cdiv(TOTAL, 256), 256, 0, stream>>>(
      W_in, Wo1, Wo1 + (size_t)C * C, Wo2, pw, cin, inv, histc);

  // hierarchical scan + order-scatter
  k_tilesum<<<NT, 256, 0, stream>>>(histc, NSEG, tsum);
  k_scantiles<<<1, 256, 0, stream>>>(tsum, NT);
  k_scanwrite<<<NT, 256, 0, stream>>>(histc, tsum, NSEG, off, next);
  k_order2<<<cdiv(TOTAL, 256), 256, 0, stream>>>(cin, cil, inv, next, pid, vsrc, vid);

  // 1) ds_mean = segment_mean(features+v_fea, inv)
  k_segmean_ds<<<cdiv(ND, 4), 256, 0, stream>>>(features, v_fea, off, vid, ds_mean);

  // 2) h1 = lrelu(ds_mean @ W1 + b1), BN1 stats
  k_gemm<128, 64, true, true, false, true>
      <<<cdiv(ND, 64), 256, 0, stream>>>(ds_mean, nullptr, nullptr, nullptr, 0.f,
                                          W1, b1, h1, stats1, ND);

  // 3) h2 = lrelu(bn1(h1) @ W2 + b2), BN2 stats   (BN1 folded into prologue)
  k_gemm<64, 64, true, true, true, true>
      <<<cdiv(ND, 64), 256, 0, stream>>>(h1, stats1, g1, beta1, 1.f / ND,
                                          W2, b2, h2, stats2, ND);

  // 4) hm = lrelu(bn2(h2) @ W3 + b3) -> big       (BN2 folded into prologue)
  k_gemm<64, 128, true, false, true, true>
      <<<cdiv(ND, 64), 256, 0, stream>>>(h2, stats2, g2, beta2, 1.f / ND,
                                          W3, b3, big, nullptr, ND);

  // 5) t = hm @ Wo1_bot + bo1                     (MFMA; t aliases ds_mean)
  k_mgemm<false, true><<<cdiv(ND, 64), 256, 0, stream>>>(
      big, Wo1b_h, Wo1b_l, bo1, t, ND);

  // 6-8) fused 1-strip chunked, pinned waves_per_eu(4,4)
  k_fused3<<<cdiv(NV, 64), 256, 0, stream>>>(
      features, v_fea, Win_h, Win_l, Wo1t_h, Wo1t_l, Wo2_h, Wo2_l,
      b_in, t, inv, bo2, big, NV);

  // 9) fused segment-mean -> output
  k_segmean_p<<<cdiv(NV2, 4), 256, 0, stream>>>(big, off, pid, vsrc, (float*)d_out);

  (void)in_sizes; (void)n_in; (void)out_size; (void)ws_size;
}